// Round 8
// baseline (323.869 us; speedup 1.0000x reference)
//
#include <hip/hip_runtime.h>

// Dtypes (established round 5): inputs int32/f32, outputs f32 (gid, score).
#define SS 4
#define BB 256
#define PP 32768
#define DD 256
#define QQ 1024          // SS*BB
#define NN 131072        // SS*PP candidate rows
#define KTOP 10
#define QTILE 128        // queries per block (4 waves x 32 q)
#define WQ 32            // q per wave (32x32 MFMA)
#define NCHUNK 64        // n-chunks
#define CHROWS 2048      // rows per chunk
#define PANEL 32         // rows per LDS panel (one 32-col tile, dual k-split chains)
#define NPANEL (CHROWS / PANEL)   // 64
#define JCH 8            // per-(q,chunk) survivors (sorted desc run)
#define MSLOT 20         // global approx survivors per q (exact-rescored)
#define ROWG 33          // padded LDS row stride in 16B granules (0-conflict, measured)
#define ROWE (ROWG * 8)  // row stride in bf16 units (264)
#define PANB (PANEL * ROWG * 16)  // 16896 B per panel buffer
#define KEYMASK 0xFFFFF800u       // keep 21 score bits, low 11 = column
#define MWS 132          // merge-stage row stride in u32 (bank-spread, 16B-aligned)
#define SMEMB 67584      // merge region: 4 waves x 32 q x 132 u32 x 4B (>= 2*PANB)

typedef __attribute__((ext_vector_type(8))) short bf16x8;
typedef __attribute__((ext_vector_type(4))) float f32x4;
typedef __attribute__((ext_vector_type(16))) float f32x16;
typedef __attribute__((ext_vector_type(4))) unsigned int u32x4;

static __device__ __forceinline__ short f2bf(float f) {   // RNE
    union { float f; unsigned u; } v; v.f = f;
    unsigned r = (v.u + 0x7FFFu + ((v.u >> 16) & 1u)) >> 16;
    return (short)r;
}
static __device__ __forceinline__ unsigned umax(unsigned a, unsigned b) { return a > b ? a : b; }
// v_med3_u32: for sorted a<=b, med3(k,a,b) == min(max(k,a),b). One VOP3 vs two.
static __device__ __forceinline__ unsigned med3u(unsigned k, unsigned a, unsigned b) {
    unsigned d;
    asm("v_med3_u32 %0, %1, %2, %3" : "=v"(d) : "v"(k), "v"(a), "v"(b));
    return d;
}
// HW packed f32->bf16 (RNE): dst.lo16 = cvt(lo), dst.hi16 = cvt(hi)
static __device__ __forceinline__ unsigned pkbf(float lo, float hi) {
    unsigned d;
    asm("v_cvt_pk_bf16_f32 %0, %1, %2" : "=v"(d) : "v"(lo), "v"(hi));
    return d;
}
static __device__ __forceinline__ bf16x8 cvt8pk(f32x4 a, f32x4 b) {
    union { u32x4 u; bf16x8 h; } c;
    c.u[0] = pkbf(a[0], a[1]); c.u[1] = pkbf(a[2], a[3]);
    c.u[2] = pkbf(b[0], b[1]); c.u[3] = pkbf(b[2], b[3]);
    return c.h;
}

// ---------------- Stage 0: qvec build only (E convert fused into score) ------------------
__global__ void prep_kernel(const int* __restrict__ rel, const int* __restrict__ head,
                            const float* __restrict__ E, const float* __restrict__ R,
                            short* __restrict__ qbf) {
    int q = blockIdx.x, d = threadIdx.x;
    int s1 = q >> 8;
    float f = E[((size_t)(s1 * PP + head[q])) * DD + d] * R[(size_t)rel[q] * DD + d];
    qbf[q * DD + d] = f2bf(f);
}

// ---------------- Stage 1: 32x32x16 bf16 MFMA (dual k-split chains) + packed-u32 top-k ----
// f32 E staged directly; PANEL=32 rows, 8 raw-f32 loads (32 VGPR hold), single drain.
// The k-chain is SPLIT into two independent accumulators (ks 0-7 -> acc0, ks 8-15 -> acc1)
// interleaved 1:1 -- halves the dependent-MFMA latency chain (round 7's 113 us was
// serial-chain bound: 16 deps x ~32cy latency, MfmaUtil 25%). Score = acc0+acc1.
__launch_bounds__(256, 2)
__global__ void score_topk_kernel(const float* __restrict__ E, const short* __restrict__ qbf,
                                  unsigned* __restrict__ parts) {
    __shared__ __align__(16) char smem[SMEMB];

    const int tid  = threadIdx.x;
    const int wave = tid >> 6;
    const int lane = tid & 63;
    const int lh   = lane >> 5;   // k-half
    const int ln   = lane & 31;
    const int mtile = blockIdx.x >> 6;   // 0..7
    const int chunk = blockIdx.x & 63;   // 0..63

    short* buf0 = (short*)smem;
    short* buf1 = (short*)(smem + PANB);

    // A fragments: A[m=lane&31][k=ks*16 + (lane>>5)*8 + j]
    bf16x8 afrag[16];
    {
        const int arow = mtile * QTILE + wave * WQ + ln;
        #pragma unroll
        for (int ks = 0; ks < 16; ks++)
            afrag[ks] = *(const bf16x8*)(qbf + arow * DD + ks * 16 + lh * 8);
    }

    // 16 per-lane 4-deep ascending lists; list r holds q_local=(r&3)+8*(r>>2)+4*lh
    unsigned lst[16][4];
    #pragma unroll
    for (int r = 0; r < 16; r++)
        #pragma unroll
        for (int i = 0; i < 4; i++) lst[r][i] = 0u;

    const int n0c = chunk * CHROWS;
    const int srow = tid >> 5, sslot = tid & 31;   // granule coords (4 granules/thread)

    // prologue: stage panel 0 into buf0 (no compute to overlap: load+cvt+write now)
    #pragma unroll
    for (int it = 0; it < 4; it++) {
        const float* src = E + (size_t)(n0c + it * 8 + srow) * DD + sslot * 8;
        f32x4 a = *(const f32x4*)src;
        f32x4 b = *(const f32x4*)(src + 4);
        *(bf16x8*)(buf0 + (it * 8 + srow) * ROWE + sslot * 8) = cvt8pk(a, b);
    }

    float stf[32];   // raw f32 panel hold (32 VGPRs, proven spill-free footprint)
    f32x16 acc0, acc1;

    #define PREF(PNEXT)                                                                \
        {                                                                              \
            const int n1 = n0c + (PNEXT) * PANEL;                                      \
            _Pragma("unroll")                                                          \
            for (int it = 0; it < 4; it++) {                                           \
                const float* src = E + (size_t)(n1 + it * 8 + srow) * DD + sslot * 8;  \
                *(f32x4*)(stf + it * 8)     = *(const f32x4*)src;                      \
                *(f32x4*)(stf + it * 8 + 4) = *(const f32x4*)(src + 4);                \
            }                                                                          \
        }
    #define MM(BUF)                                                                    \
        {                                                                              \
            _Pragma("unroll")                                                          \
            for (int r = 0; r < 16; r++) { acc0[r] = 256.0f; acc1[r] = 0.0f; }         \
            const short* b0 = (BUF) + ln * ROWE + lh * 8;                              \
            _Pragma("unroll")                                                          \
            for (int ks = 0; ks < 8; ks++) {                                           \
                bf16x8 x0 = *(const bf16x8*)(b0 + ks * 16);                            \
                bf16x8 x1 = *(const bf16x8*)(b0 + (ks + 8) * 16);                      \
                acc0 = __builtin_amdgcn_mfma_f32_32x32x16_bf16(afrag[ks],     x0, acc0, 0, 0, 0); \
                acc1 = __builtin_amdgcn_mfma_f32_32x32x16_bf16(afrag[ks + 8], x1, acc1, 0, 0, 0); \
            }                                                                          \
        }
    #define KEYS1(PIDX)                                                                \
        {                                                                              \
            const unsigned cc = (unsigned)((PIDX) * 32 + ln);                          \
            _Pragma("unroll")                                                          \
            for (int r = 0; r < 16; r++) {                                             \
                float sv = acc0[r] + acc1[r];                                          \
                unsigned key = (__float_as_uint(sv) & KEYMASK) | cc;                   \
                unsigned n0 = med3u(key, lst[r][0], lst[r][1]);                        \
                unsigned n1k = med3u(key, lst[r][1], lst[r][2]);                       \
                unsigned n2 = med3u(key, lst[r][2], lst[r][3]);                        \
                lst[r][3] = umax(key, lst[r][3]);                                      \
                lst[r][0] = n0; lst[r][1] = n1k; lst[r][2] = n2;                       \
            }                                                                          \
        }
    #define WR(BUF)                                                                    \
        {                                                                              \
            _Pragma("unroll")                                                          \
            for (int e = 0; e < 32; e++) asm volatile("" : "+v"(stf[e]));              \
            _Pragma("unroll")                                                          \
            for (int it = 0; it < 4; it++) {                                           \
                f32x4 a = *(const f32x4*)(stf + it * 8);                               \
                f32x4 b = *(const f32x4*)(stf + it * 8 + 4);                           \
                *(bf16x8*)((BUF) + (it * 8 + srow) * ROWE + sslot * 8) = cvt8pk(a, b); \
            }                                                                          \
        }

    // 2 panels per iteration, parity-static ping-pong (NPANEL=64 even).
    // Per panel: barrier -> issue loads -> MFMA(2 indep chains)+KEYS -> drain+cvt+write.
    for (int p = 0; p < NPANEL; p += 2) {
        __syncthreads();
        PREF(p + 1);
        MM(buf0); KEYS1(p);
        WR(buf1);
        __syncthreads();
        if (p + 2 < NPANEL) PREF(p + 2);
        MM(buf1); KEYS1(p + 1);
        if (p + 2 < NPANEL) WR(buf0);
    }

    #undef PREF
    #undef MM
    #undef KEYS1
    #undef WR

    // ---- end of chunk: per-wave dump (32 q x 128 keys), lanes<32 build top-8 runs ----
    __syncthreads();   // all panel reads complete; reuse whole smem
    unsigned* mw = (unsigned*)smem + (size_t)wave * (WQ * MWS);
    #pragma unroll
    for (int r = 0; r < 16; r++) {
        int q = (r & 3) + 8 * (r >> 2) + 4 * lh;
        u32x4 v; v[0] = lst[r][0]; v[1] = lst[r][1]; v[2] = lst[r][2]; v[3] = lst[r][3];
        *(u32x4*)(mw + q * MWS + ln * 4) = v;   // same-wave LDS, program-order visible
    }
    if (lane < 32) {   // lane = q_local: top-8 of its 128 keys
        unsigned rr[JCH];
        #pragma unroll
        for (int i = 0; i < JCH; i++) rr[i] = 0u;
        #pragma unroll
        for (int j = 0; j < 32; j++) {
            u32x4 v = *(const u32x4*)(mw + lane * MWS + j * 4);
            #pragma unroll
            for (int e = 0; e < 4; e++) {
                unsigned x = v[e];
                unsigned t0 = med3u(x, rr[0], rr[1]);
                unsigned t1 = med3u(x, rr[1], rr[2]);
                unsigned t2 = med3u(x, rr[2], rr[3]);
                unsigned t3 = med3u(x, rr[3], rr[4]);
                unsigned t4 = med3u(x, rr[4], rr[5]);
                unsigned t5 = med3u(x, rr[5], rr[6]);
                unsigned t6 = med3u(x, rr[6], rr[7]);
                rr[7] = umax(x, rr[7]);
                rr[0]=t0; rr[1]=t1; rr[2]=t2; rr[3]=t3; rr[4]=t4; rr[5]=t5; rr[6]=t6;
            }
        }
        const int qg = mtile * QTILE + wave * WQ + lane;
        unsigned* dst = parts + ((size_t)qg * NCHUNK + chunk) * JCH;
        #pragma unroll
        for (int i = 0; i < JCH; i++) dst[i] = rr[JCH - 1 - i];   // descending run
    }
}

// ---------------- Stage 2: fused merge (lane=chunk, 20 pops) + exact f32 rescore ----------
__global__ void finalize_kernel(const int* __restrict__ rel, const int* __restrict__ head,
                                const float* __restrict__ E, const float* __restrict__ R,
                                const unsigned* __restrict__ parts, float* __restrict__ out) {
    __shared__ float qv[DD];
    __shared__ int   gl[MSLOT];
    __shared__ float rsc[MSLOT];
    __shared__ int   rgid[MSLOT];

    const int q = blockIdx.x;
    const int tid = threadIdx.x;
    const int wave = tid >> 6, lane = tid & 63;
    const int s1 = q >> 8;

    qv[tid] = E[((size_t)(s1 * PP + head[q])) * DD + tid] * R[(size_t)rel[q] * DD + tid];

    if (wave == 0) {   // lane = chunk; 20 argmax-pops over 64 sorted-desc runs of 8
        unsigned run[JCH];
        const unsigned* src = parts + ((size_t)q * NCHUNK + lane) * JCH;
        #pragma unroll
        for (int j = 0; j < JCH; j++) run[j] = src[j];
        for (int r = 0; r < MSLOT; r++) {
            unsigned best = run[0]; int bl = lane;
            #pragma unroll
            for (int off = 32; off >= 1; off >>= 1) {
                unsigned ob = __shfl_xor(best, off);
                int ol = __shfl_xor(bl, off);
                if (ob > best || (ob == best && ol < bl)) { best = ob; bl = ol; }
            }
            if (lane == bl) {
                int col = (int)(best & 0x7FFu);
                int n = lane * CHROWS + col;
                gl[r] = ((n & (PP - 1)) << 2) | (n >> 15);   // gid = p*4 + s2
                #pragma unroll
                for (int j = 0; j < JCH - 1; j++) run[j] = run[j + 1];
                run[JCH - 1] = 0u;
            }
        }
    }
    __syncthreads();

    // exact f32 rescore: wave w handles candidates w*5 .. w*5+4
    f32x4 qq = *(const f32x4*)(qv + lane * 4);
    #pragma unroll
    for (int c = 0; c < MSLOT / 4; c++) {
        int j = wave * (MSLOT / 4) + c;
        int gid = gl[j];
        int n = (gid & 3) * PP + (gid >> 2);
        f32x4 ev = *(const f32x4*)(E + (size_t)n * DD + lane * 4);
        f32x4 p = qq * ev;
        float s = (p[0] + p[1]) + (p[2] + p[3]);
        #pragma unroll
        for (int off = 32; off >= 1; off >>= 1) s += __shfl_xor(s, off);
        if (lane == 0) { rsc[j] = s; rgid[j] = gid; }
    }
    __syncthreads();

    if (tid < 64) {   // wave 0: 10 argmax-pops over 20 exact scores
        float a = (tid < MSLOT) ? rsc[tid] : -1e30f;
        int   g = (tid < MSLOT) ? rgid[tid] : 0;
        for (int r = 0; r < KTOP; r++) {
            float ps = a; int pg = g; int plm = tid;
            #pragma unroll
            for (int off = 32; off >= 1; off >>= 1) {
                float os = __shfl_xor(ps, off);
                int   og = __shfl_xor(pg, off);
                int   ol = __shfl_xor(plm, off);
                if (os > ps || (os == ps && ol < plm)) { ps = os; pg = og; plm = ol; }
            }
            if (tid == 0) {
                out[q * KTOP + r]             = (float)pg;   // Output 0: gid
                out[QQ * KTOP + q * KTOP + r] = ps;          // Output 1: score
            }
            if (tid == plm) a = -1e30f;
        }
    }
}

extern "C" void kernel_launch(void* const* d_in, const int* in_sizes, int n_in,
                              void* d_out, int out_size, void* d_ws, size_t ws_size,
                              hipStream_t stream) {
    const int*   rel  = (const int*)d_in[0];
    const int*   head = (const int*)d_in[1];
    const float* E    = (const float*)d_in[2];
    const float* R    = (const float*)d_in[3];

    char* ws = (char*)d_ws;
    short* qbf = (short*)ws;                                   //   524,288 B
    unsigned* parts = (unsigned*)(ws + (size_t)QQ * DD * 2);   // 2,097,152 B

    prep_kernel<<<dim3(QQ), dim3(256), 0, stream>>>(rel, head, E, R, qbf);
    score_topk_kernel<<<dim3((QQ / QTILE) * NCHUNK), dim3(256), 0, stream>>>(E, qbf, parts);
    finalize_kernel<<<dim3(QQ), dim3(256), 0, stream>>>(rel, head, E, R, parts, (float*)d_out);
}

// Round 9
// 272.956 us; speedup vs baseline: 1.1865x; 1.1865x over previous
//
#include <hip/hip_runtime.h>

// Dtypes (established round 5): inputs int32/f32, outputs f32 (gid, score).
#define SS 4
#define BB 256
#define PP 32768
#define DD 256
#define QQ 1024          // SS*BB
#define NN 131072        // SS*PP candidate rows
#define KTOP 10
#define QTILE 128        // queries per block (4 waves x 32 q)
#define WQ 32            // q per wave (32x32 MFMA)
#define NCHUNK 64        // n-chunks
#define CHROWS 2048      // rows per chunk
#define PANEL 32         // rows per LDS panel (single 32-col MFMA chain)
#define NPANEL (CHROWS / PANEL)   // 64
#define JCH 8            // per-(q,chunk) survivors (sorted desc run)
#define MSLOT 20         // global approx survivors per q (exact-rescored)
#define ROWG 33          // padded LDS row stride in 16B granules (0-conflict, measured)
#define ROWE (ROWG * 8)  // row stride in bf16 units (264)
#define PANB (PANEL * ROWG * 16)  // 16896 B per panel buffer; 3 buffers = 50688 B
#define KEYMASK 0xFFFFF800u       // keep 21 score bits, low 11 = column
#define MWS 132          // merge-stage row stride in u32 (bank-spread, 16B-aligned)
#define SMEMB 67584      // merge region: 4 waves x 32 q x 132 u32 x 4B (>= 3*PANB)

typedef __attribute__((ext_vector_type(8))) short bf16x8;
typedef __attribute__((ext_vector_type(4))) float f32x4;
typedef __attribute__((ext_vector_type(16))) float f32x16;
typedef __attribute__((ext_vector_type(4))) unsigned int u32x4;

static __device__ __forceinline__ short f2bf(float f) {   // RNE
    union { float f; unsigned u; } v; v.f = f;
    unsigned r = (v.u + 0x7FFFu + ((v.u >> 16) & 1u)) >> 16;
    return (short)r;
}
static __device__ __forceinline__ unsigned umax(unsigned a, unsigned b) { return a > b ? a : b; }
// v_med3_u32: for sorted a<=b, med3(k,a,b) == min(max(k,a),b). One VOP3 vs two.
static __device__ __forceinline__ unsigned med3u(unsigned k, unsigned a, unsigned b) {
    unsigned d;
    asm("v_med3_u32 %0, %1, %2, %3" : "=v"(d) : "v"(k), "v"(a), "v"(b));
    return d;
}
// HW packed f32->bf16 (RNE): dst.lo16 = cvt(lo), dst.hi16 = cvt(hi)
static __device__ __forceinline__ unsigned pkbf(float lo, float hi) {
    unsigned d;
    asm("v_cvt_pk_bf16_f32 %0, %1, %2" : "=v"(d) : "v"(lo), "v"(hi));
    return d;
}
static __device__ __forceinline__ bf16x8 cvt8pk(f32x4 a, f32x4 b) {
    union { u32x4 u; bf16x8 h; } c;
    c.u[0] = pkbf(a[0], a[1]); c.u[1] = pkbf(a[2], a[3]);
    c.u[2] = pkbf(b[0], b[1]); c.u[3] = pkbf(b[2], b[3]);
    return c.h;
}

// ---------------- Stage 0: qvec build only (E convert fused into score) ------------------
__global__ void prep_kernel(const int* __restrict__ rel, const int* __restrict__ head,
                            const float* __restrict__ E, const float* __restrict__ R,
                            short* __restrict__ qbf) {
    int q = blockIdx.x, d = threadIdx.x;
    int s1 = q >> 8;
    float f = E[((size_t)(s1 * PP + head[q])) * DD + d] * R[(size_t)rel[q] * DD + d];
    qbf[q * DD + d] = f2bf(f);
}

// ---------------- Stage 1: 32x32x16 bf16 MFMA + packed-u32 top-k, 3-deep pipeline ---------
// f32 E staged directly. TRIPLE-buffered LDS: panel p+1's loads issue during panel p-1
// (PREF), convert+write at the TOP of panel p (WR), compute at p+1 (MM). The stf drain
// thus has a full panel (~1000cy) of cover vs round 7's same-panel ~400cy, and any
// residual wait folds into the barrier. stf stays 32 VGPRs (register-neutral vs r7).
__launch_bounds__(256, 2)
__global__ void score_topk_kernel(const float* __restrict__ E, const short* __restrict__ qbf,
                                  unsigned* __restrict__ parts) {
    __shared__ __align__(16) char smem[SMEMB];

    const int tid  = threadIdx.x;
    const int wave = tid >> 6;
    const int lane = tid & 63;
    const int lh   = lane >> 5;   // k-half
    const int ln   = lane & 31;
    const int mtile = blockIdx.x >> 6;   // 0..7
    const int chunk = blockIdx.x & 63;   // 0..63

    // A fragments: A[m=lane&31][k=ks*16 + (lane>>5)*8 + j]
    bf16x8 afrag[16];
    {
        const int arow = mtile * QTILE + wave * WQ + ln;
        #pragma unroll
        for (int ks = 0; ks < 16; ks++)
            afrag[ks] = *(const bf16x8*)(qbf + arow * DD + ks * 16 + lh * 8);
    }

    // 16 per-lane 4-deep ascending lists; list r holds q_local=(r&3)+8*(r>>2)+4*lh
    unsigned lst[16][4];
    #pragma unroll
    for (int r = 0; r < 16; r++)
        #pragma unroll
        for (int i = 0; i < 4; i++) lst[r][i] = 0u;

    const int n0c = chunk * CHROWS;
    const int srow = tid >> 5, sslot = tid & 31;   // granule coords (4 granules/thread)
    const float* pe = E + (size_t)(n0c + srow) * DD + sslot * 8;   // per-thread base

    // prologue: stage panel 0 directly into buf0 (load+cvt+write, serial — once)
    #pragma unroll
    for (int it = 0; it < 4; it++) {
        f32x4 a = *(const f32x4*)(pe + it * 2048);
        f32x4 b = *(const f32x4*)(pe + it * 2048 + 4);
        *(bf16x8*)((short*)smem + (it * 8 + srow) * ROWE + sslot * 8) = cvt8pk(a, b);
    }

    float stf[32];   // raw f32 panel hold (32 VGPRs, proven spill-free footprint)
    // PREF panel 1 into stf (written to buf1 at top of panel 0)
    #pragma unroll
    for (int it = 0; it < 4; it++) {
        *(f32x4*)(stf + it * 8)     = *(const f32x4*)(pe + 8192 + it * 2048);
        *(f32x4*)(stf + it * 8 + 4) = *(const f32x4*)(pe + 8192 + it * 2048 + 4);
    }
    const float* pref_p = pe + 16384;   // panel 2 onward, advances 8192 f32 per panel

    int omm = 0, owr = PANB;   // 3-buffer rotation: omm=(p%3), owr=((p+1)%3)

    for (int p = 0; p < NPANEL; p++) {
        __syncthreads();   // buf[omm] fully written (WR of panel p-1); buf[owr] free

        if (p + 1 < NPANEL) {
            // fence: raw values must exist HERE -> compiler cannot convert early
            #pragma unroll
            for (int e = 0; e < 32; e++) asm volatile("" : "+v"(stf[e]));
            short* bw = (short*)(smem + owr);
            #pragma unroll
            for (int it = 0; it < 4; it++) {   // cvt+write panel p+1 (loads ~1 panel old)
                f32x4 a = *(const f32x4*)(stf + it * 8);
                f32x4 b = *(const f32x4*)(stf + it * 8 + 4);
                *(bf16x8*)(bw + (it * 8 + srow) * ROWE + sslot * 8) = cvt8pk(a, b);
            }
        }
        if (p + 2 < NPANEL) {   // issue loads for panel p+2 (in flight across next barrier)
            #pragma unroll
            for (int it = 0; it < 4; it++) {
                *(f32x4*)(stf + it * 8)     = *(const f32x4*)(pref_p + it * 2048);
                *(f32x4*)(stf + it * 8 + 4) = *(const f32x4*)(pref_p + it * 2048 + 4);
            }
            pref_p += 8192;
        }

        // single accumulator chain (C-operand forwarding makes serial accumulate cheap)
        f32x16 acc;
        #pragma unroll
        for (int r = 0; r < 16; r++) acc[r] = 256.0f;
        const short* b0 = (const short*)(smem + omm) + ln * ROWE + lh * 8;
        #pragma unroll
        for (int ks = 0; ks < 16; ks++) {
            bf16x8 x0 = *(const bf16x8*)(b0 + ks * 16);
            acc = __builtin_amdgcn_mfma_f32_32x32x16_bf16(afrag[ks], x0, acc, 0, 0, 0);
        }

        // D: col=lane&31, row=(reg&3)+8*(reg>>2)+4*lh -> one key per owned (q,col)
        const unsigned cc = (unsigned)(p * PANEL + ln);
        #pragma unroll
        for (int r = 0; r < 16; r++) {
            unsigned key = (__float_as_uint(acc[r]) & KEYMASK) | cc;
            unsigned n0 = med3u(key, lst[r][0], lst[r][1]);
            unsigned n1k = med3u(key, lst[r][1], lst[r][2]);
            unsigned n2 = med3u(key, lst[r][2], lst[r][3]);
            lst[r][3] = umax(key, lst[r][3]);
            lst[r][0] = n0; lst[r][1] = n1k; lst[r][2] = n2;
        }

        int nx = owr + PANB; if (nx == 3 * PANB) nx = 0;   // rotate buffers
        omm = owr; owr = nx;
    }

    // ---- end of chunk: per-wave dump (32 q x 128 keys), lanes<32 build top-8 runs ----
    __syncthreads();   // all panel reads complete; reuse whole smem
    unsigned* mw = (unsigned*)smem + (size_t)wave * (WQ * MWS);
    #pragma unroll
    for (int r = 0; r < 16; r++) {
        int q = (r & 3) + 8 * (r >> 2) + 4 * lh;
        u32x4 v; v[0] = lst[r][0]; v[1] = lst[r][1]; v[2] = lst[r][2]; v[3] = lst[r][3];
        *(u32x4*)(mw + q * MWS + ln * 4) = v;   // same-wave LDS, program-order visible
    }
    if (lane < 32) {   // lane = q_local: top-8 of its 128 keys
        unsigned rr[JCH];
        #pragma unroll
        for (int i = 0; i < JCH; i++) rr[i] = 0u;
        #pragma unroll
        for (int j = 0; j < 32; j++) {
            u32x4 v = *(const u32x4*)(mw + lane * MWS + j * 4);
            #pragma unroll
            for (int e = 0; e < 4; e++) {
                unsigned x = v[e];
                unsigned t0 = med3u(x, rr[0], rr[1]);
                unsigned t1 = med3u(x, rr[1], rr[2]);
                unsigned t2 = med3u(x, rr[2], rr[3]);
                unsigned t3 = med3u(x, rr[3], rr[4]);
                unsigned t4 = med3u(x, rr[4], rr[5]);
                unsigned t5 = med3u(x, rr[5], rr[6]);
                unsigned t6 = med3u(x, rr[6], rr[7]);
                rr[7] = umax(x, rr[7]);
                rr[0]=t0; rr[1]=t1; rr[2]=t2; rr[3]=t3; rr[4]=t4; rr[5]=t5; rr[6]=t6;
            }
        }
        const int qg = mtile * QTILE + wave * WQ + lane;
        unsigned* dst = parts + ((size_t)qg * NCHUNK + chunk) * JCH;
        #pragma unroll
        for (int i = 0; i < JCH; i++) dst[i] = rr[JCH - 1 - i];   // descending run
    }
}

// ---------------- Stage 2: fused merge (lane=chunk, 20 pops) + exact f32 rescore ----------
__global__ void finalize_kernel(const int* __restrict__ rel, const int* __restrict__ head,
                                const float* __restrict__ E, const float* __restrict__ R,
                                const unsigned* __restrict__ parts, float* __restrict__ out) {
    __shared__ float qv[DD];
    __shared__ int   gl[MSLOT];
    __shared__ float rsc[MSLOT];
    __shared__ int   rgid[MSLOT];

    const int q = blockIdx.x;
    const int tid = threadIdx.x;
    const int wave = tid >> 6, lane = tid & 63;
    const int s1 = q >> 8;

    qv[tid] = E[((size_t)(s1 * PP + head[q])) * DD + tid] * R[(size_t)rel[q] * DD + tid];

    if (wave == 0) {   // lane = chunk; 20 argmax-pops over 64 sorted-desc runs of 8
        unsigned run[JCH];
        const unsigned* src = parts + ((size_t)q * NCHUNK + lane) * JCH;
        #pragma unroll
        for (int j = 0; j < JCH; j++) run[j] = src[j];
        for (int r = 0; r < MSLOT; r++) {
            unsigned best = run[0]; int bl = lane;
            #pragma unroll
            for (int off = 32; off >= 1; off >>= 1) {
                unsigned ob = __shfl_xor(best, off);
                int ol = __shfl_xor(bl, off);
                if (ob > best || (ob == best && ol < bl)) { best = ob; bl = ol; }
            }
            if (lane == bl) {
                int col = (int)(best & 0x7FFu);
                int n = lane * CHROWS + col;
                gl[r] = ((n & (PP - 1)) << 2) | (n >> 15);   // gid = p*4 + s2
                #pragma unroll
                for (int j = 0; j < JCH - 1; j++) run[j] = run[j + 1];
                run[JCH - 1] = 0u;
            }
        }
    }
    __syncthreads();

    // exact f32 rescore: wave w handles candidates w*5 .. w*5+4
    f32x4 qq = *(const f32x4*)(qv + lane * 4);
    #pragma unroll
    for (int c = 0; c < MSLOT / 4; c++) {
        int j = wave * (MSLOT / 4) + c;
        int gid = gl[j];
        int n = (gid & 3) * PP + (gid >> 2);
        f32x4 ev = *(const f32x4*)(E + (size_t)n * DD + lane * 4);
        f32x4 p = qq * ev;
        float s = (p[0] + p[1]) + (p[2] + p[3]);
        #pragma unroll
        for (int off = 32; off >= 1; off >>= 1) s += __shfl_xor(s, off);
        if (lane == 0) { rsc[j] = s; rgid[j] = gid; }
    }
    __syncthreads();

    if (tid < 64) {   // wave 0: 10 argmax-pops over 20 exact scores
        float a = (tid < MSLOT) ? rsc[tid] : -1e30f;
        int   g = (tid < MSLOT) ? rgid[tid] : 0;
        for (int r = 0; r < KTOP; r++) {
            float ps = a; int pg = g; int plm = tid;
            #pragma unroll
            for (int off = 32; off >= 1; off >>= 1) {
                float os = __shfl_xor(ps, off);
                int   og = __shfl_xor(pg, off);
                int   ol = __shfl_xor(plm, off);
                if (os > ps || (os == ps && ol < plm)) { ps = os; pg = og; plm = ol; }
            }
            if (tid == 0) {
                out[q * KTOP + r]             = (float)pg;   // Output 0: gid
                out[QQ * KTOP + q * KTOP + r] = ps;          // Output 1: score
            }
            if (tid == plm) a = -1e30f;
        }
    }
}

extern "C" void kernel_launch(void* const* d_in, const int* in_sizes, int n_in,
                              void* d_out, int out_size, void* d_ws, size_t ws_size,
                              hipStream_t stream) {
    const int*   rel  = (const int*)d_in[0];
    const int*   head = (const int*)d_in[1];
    const float* E    = (const float*)d_in[2];
    const float* R    = (const float*)d_in[3];

    char* ws = (char*)d_ws;
    short* qbf = (short*)ws;                                   //   524,288 B
    unsigned* parts = (unsigned*)(ws + (size_t)QQ * DD * 2);   // 2,097,152 B

    prep_kernel<<<dim3(QQ), dim3(256), 0, stream>>>(rel, head, E, R, qbf);
    score_topk_kernel<<<dim3((QQ / QTILE) * NCHUNK), dim3(256), 0, stream>>>(E, qbf, parts);
    finalize_kernel<<<dim3(QQ), dim3(256), 0, stream>>>(rel, head, E, R, parts, (float*)d_out);
}